// Round 7
// baseline (9.739 us; speedup 1.0000x reference)
//
#include <hip/hip_runtime.h>

#define BATCH 1024
#define FEAT_DIM 512
#define NWORK 64            // worker blocks; block 0 is a dedicated finisher
#define MAGIC 0x5CA1AB1Eu

// Grid = 65 blocks x 256 threads.
//   Block 0: finisher only. Spins (relaxed agent-scope polls) on the 64
//            worker flags, one per lane; acquire fence; reduces the 64
//            partials; writes out; resets flags to 0 (deterministic replay;
//            poison 0xAA != MAGIC so the first post-poison replay is safe).
//   Blocks 1..64: 4 waves x 4 samples/wave = 16 samples each. Per lane:
//            16 independent float4 loads in flight (8 of x, 8 of gathered
//            center rows). Labels load first to overlap the label->center
//            dependent chain. Wave shuffle-reduce, LDS combine of 4 waves,
//            thread 0 publishes partial + release flag at agent scope.
__global__ __launch_bounds__(256) void cl_fused(
    const float* __restrict__ x,
    const int* __restrict__ labels,
    const float* __restrict__ centers,
    float* __restrict__ partial,          // 64 floats
    unsigned int* __restrict__ flags,     // 64 uints (separate 1KB region)
    float* __restrict__ out)
{
    const int wave = threadIdx.x >> 6;
    const int lane = threadIdx.x & 63;

    if (blockIdx.x == 0) {
        // ---- Finisher ----
        if (wave == 0) {
            bool done = false;
            while (!__all(done)) {
                done = (__hip_atomic_load(&flags[lane], __ATOMIC_RELAXED,
                                          __HIP_MEMORY_SCOPE_AGENT) == MAGIC);
            }
            __builtin_amdgcn_fence(__ATOMIC_ACQUIRE, "agent");

            float t = __hip_atomic_load(&partial[lane], __ATOMIC_RELAXED,
                                        __HIP_MEMORY_SCOPE_AGENT);
            #pragma unroll
            for (int off = 32; off > 0; off >>= 1)
                t += __shfl_down(t, off, 64);

            if (lane == 0) out[0] = t * (0.5f / (float)BATCH);

            __hip_atomic_store(&flags[lane], 0u, __ATOMIC_RELAXED,
                               __HIP_MEMORY_SCOPE_AGENT);
        }
        return;
    }

    // ---- Workers ----
    const int blk = blockIdx.x - 1;            // 0..63
    const int b0  = blk * 16 + wave * 4;       // 4 consecutive samples

    const int lab0 = labels[b0];
    const int lab1 = labels[b0 + 1];
    const int lab2 = labels[b0 + 2];
    const int lab3 = labels[b0 + 3];

    const float4* __restrict__ xr =
        reinterpret_cast<const float4*>(x + (size_t)b0 * FEAT_DIM);
    const float4* __restrict__ c0 =
        reinterpret_cast<const float4*>(centers + (size_t)lab0 * FEAT_DIM);
    const float4* __restrict__ c1 =
        reinterpret_cast<const float4*>(centers + (size_t)lab1 * FEAT_DIM);
    const float4* __restrict__ c2 =
        reinterpret_cast<const float4*>(centers + (size_t)lab2 * FEAT_DIM);
    const float4* __restrict__ c3 =
        reinterpret_cast<const float4*>(centers + (size_t)lab3 * FEAT_DIM);

    // 8 x-loads (x rows are consecutive: 4 samples x 128 float4 each).
    const float4 xa0 = xr[lane];
    const float4 xa1 = xr[lane + 64];
    const float4 xb0 = xr[lane + 128];
    const float4 xb1 = xr[lane + 192];
    const float4 xc0 = xr[lane + 256];
    const float4 xc1 = xr[lane + 320];
    const float4 xd0 = xr[lane + 384];
    const float4 xd1 = xr[lane + 448];
    // 8 center-loads (gathered rows).
    const float4 ca0 = c0[lane];
    const float4 ca1 = c0[lane + 64];
    const float4 cb0 = c1[lane];
    const float4 cb1 = c1[lane + 64];
    const float4 cc0 = c2[lane];
    const float4 cc1 = c2[lane + 64];
    const float4 cd0 = c3[lane];
    const float4 cd1 = c3[lane + 64];

    float s = 0.f;
    {
        float d;
        d = xa0.x - ca0.x; s += d * d;  d = xa0.y - ca0.y; s += d * d;
        d = xa0.z - ca0.z; s += d * d;  d = xa0.w - ca0.w; s += d * d;
        d = xa1.x - ca1.x; s += d * d;  d = xa1.y - ca1.y; s += d * d;
        d = xa1.z - ca1.z; s += d * d;  d = xa1.w - ca1.w; s += d * d;
        d = xb0.x - cb0.x; s += d * d;  d = xb0.y - cb0.y; s += d * d;
        d = xb0.z - cb0.z; s += d * d;  d = xb0.w - cb0.w; s += d * d;
        d = xb1.x - cb1.x; s += d * d;  d = xb1.y - cb1.y; s += d * d;
        d = xb1.z - cb1.z; s += d * d;  d = xb1.w - cb1.w; s += d * d;
        d = xc0.x - cc0.x; s += d * d;  d = xc0.y - cc0.y; s += d * d;
        d = xc0.z - cc0.z; s += d * d;  d = xc0.w - cc0.w; s += d * d;
        d = xc1.x - cc1.x; s += d * d;  d = xc1.y - cc1.y; s += d * d;
        d = xc1.z - cc1.z; s += d * d;  d = xc1.w - cc1.w; s += d * d;
        d = xd0.x - cd0.x; s += d * d;  d = xd0.y - cd0.y; s += d * d;
        d = xd0.z - cd0.z; s += d * d;  d = xd0.w - cd0.w; s += d * d;
        d = xd1.x - cd1.x; s += d * d;  d = xd1.y - cd1.y; s += d * d;
        d = xd1.z - cd1.z; s += d * d;  d = xd1.w - cd1.w; s += d * d;
    }

    #pragma unroll
    for (int off = 32; off > 0; off >>= 1)
        s += __shfl_down(s, off, 64);

    __shared__ float wsum[4];
    if (lane == 0) wsum[wave] = s;
    __syncthreads();

    if (threadIdx.x == 0) {
        const float p = wsum[0] + wsum[1] + wsum[2] + wsum[3];
        __hip_atomic_store(&partial[blk], p,
                           __ATOMIC_RELAXED, __HIP_MEMORY_SCOPE_AGENT);
        __hip_atomic_store(&flags[blk], MAGIC,
                           __ATOMIC_RELEASE, __HIP_MEMORY_SCOPE_AGENT);
    }
}

extern "C" void kernel_launch(void* const* d_in, const int* in_sizes, int n_in,
                              void* d_out, int out_size, void* d_ws, size_t ws_size,
                              hipStream_t stream) {
    const float* x       = (const float*)d_in[0];
    const int*   labels  = (const int*)d_in[1];
    const float* centers = (const float*)d_in[2];
    float*       out     = (float*)d_out;

    float*        partial = (float*)d_ws;                        // 64 floats
    unsigned int* flags   = (unsigned int*)((char*)d_ws + 1024); // 64 uints

    cl_fused<<<NWORK + 1, 256, 0, stream>>>(x, labels, centers, partial, flags, out);
}